// Round 8
// baseline (377.326 us; speedup 1.0000x reference)
//
#include <hip/hip_runtime.h>

typedef unsigned short ushort_t;
typedef unsigned int uint_t;

typedef ushort_t ushortx8 __attribute__((ext_vector_type(8)));
typedef ushort_t ushortx4 __attribute__((ext_vector_type(4)));
typedef __bf16 bf16x8 __attribute__((ext_vector_type(8)));
typedef float f32x4 __attribute__((ext_vector_type(4)));

#define NCC 8192
#define NGG 4096
#define NPP 140
// LDS tile row stride (elements): multiple of 8 so ushortx8 (align 16) LDS ops
// are 16B-aligned; bank step 44 dwords == 12 mod 32 => 2-way aliasing (free).
#define LDS_STR 88
// Count kernel: edges per block (1024 thr x 16). Bigger => better atomic dedup,
// fewer blocks => less CU parallelism. 16K: ~270K global atomics vs 850K flat.
#define CEPB 16384

__device__ __forceinline__ float bf2f(ushort_t u) {
    uint_t i = ((uint_t)u) << 16;
    float f;
    __builtin_memcpy(&f, &i, 4);
    return f;
}
__device__ __forceinline__ ushort_t f2bf(float f) {
    uint_t i;
    __builtin_memcpy(&i, &f, 4);
    uint_t r = (i + 0x7FFFu + ((i >> 16) & 1u)) >> 16;
    return (ushort_t)r;
}
__device__ __forceinline__ float scrub(float x) {  // insurance: non-finite -> 0
    return __builtin_isfinite(x) ? x : 0.f;
}
__device__ __forceinline__ float selu_f(float x) {
    return x > 0.f ? 1.0507009873554805f * x : 1.7580993408473766f * expm1f(x);
}
__device__ __forceinline__ float wsum64(float x) {
    for (int o = 32; o; o >>= 1) x += __shfl_xor(x, o, 64);
    return x;
}

// ---------------- zero fill ----------------
__global__ __launch_bounds__(256) void sc_zero1(int* __restrict__ a, int na) {
    int i = blockIdx.x * 256 + threadIdx.x;
    if (i < na) a[i] = 0;
}

// ================= job structs =================
struct CountJob {
    const int* dst;
    const int* src;
    const float* w;
    uint_t* pw;      // packed (bf16(w)<<16)|src, edge order
    ushort_t* rank;  // rank within dst group
    int E;
    int nbins;
    int* deg;
    int bstart;
};
struct CountBatch {
    CountJob j[6];
};
struct TrJob {
    const float* src;
    ushort_t* dst;
    int K, N, nx, nxy;
    int bstart;
};
struct TrBatch {
    TrJob j[6];
};
struct FillJob {
    const int* dst;
    const uint_t* pw;
    const ushort_t* rank;
    int E;
    const int* offs;
    uint_t* ep;
    int bstart;
};
struct FillBatch {
    FillJob j[6];
};

// ===== merged dispatch: degree count (replicated LDS hist) | feat bf16 cvt =====
// r0: LDS-hist dedup cut 850K global atomics to ~270K (53us -> off top-5).
// r2: backfilled with the f32->bf16 feature cvt (768 BW-bound blocks).
// r6: REPLICATED histogram — sym/ppi push 16K edges into 140 bins (~117
// same-address LDS-atomic RMWs per bin per block, serialized). REP=8 replicas
// for nb<=1024 (REP=2 for 4096, 1 for 8192) cut same-address contention 8x.
// Pass B prefix-sums replicas into one global range reservation; ranks unique.
struct CountArgs {
    CountBatch cb;
    int bsC;
    const float* cf;
    ushort_t* cf16;
    int nbC;  // cell cvt blocks (8192 elems each)
    const float* gf;
    ushort_t* gf16;
};
__global__ __launch_bounds__(1024) void sc_count(CountArgs ca) {
    __shared__ int hist[NCC];  // 32KB; [0, nb*rep) used
    int bx = blockIdx.x;
    const int tid = threadIdx.x;
    if (bx >= ca.bsC) {  // ---- cvt role ----
        bx -= ca.bsC;
        const float* src;
        ushort_t* dst;
        if (bx < ca.nbC) {
            src = ca.cf;
            dst = ca.cf16;
        } else {
            bx -= ca.nbC;
            src = ca.gf;
            dst = ca.gf16;
        }
        size_t i = ((size_t)bx * 1024 + tid) * 8;  // spans exact multiples of 8192
        float4 f0 = *(const float4*)(src + i);
        float4 f1 = *(const float4*)(src + i + 4);
        ushortx8 v;
        v[0] = f2bf(f0.x);
        v[1] = f2bf(f0.y);
        v[2] = f2bf(f0.z);
        v[3] = f2bf(f0.w);
        v[4] = f2bf(f1.x);
        v[5] = f2bf(f1.y);
        v[6] = f2bf(f1.z);
        v[7] = f2bf(f1.w);
        *(ushortx8*)(dst + i) = v;
        return;
    }
    int r = 0;
#pragma unroll
    for (int i = 1; i < 6; ++i) r = (bx >= ca.cb.j[i].bstart) ? i : r;
    const CountJob& J = ca.cb.j[r];
    const int nb = J.nbins;
    const int rep = nb <= 1024 ? 8 : (nb <= 4096 ? 2 : 1);
    const int qoff = (tid & (rep - 1)) * nb;
    const int tot_bins = nb * rep;  // <= NCC by construction
    for (int b = tid; b < tot_bins; b += 1024) hist[b] = 0;
    __syncthreads();
    const int e0 = (bx - J.bstart) * CEPB;
    ushort_t lrk[16];
#pragma unroll
    for (int u = 0; u < 16; ++u) {
        int e = e0 + u * 1024 + tid;
        if (e < J.E) {
            int d = J.dst[e];
            lrk[u] = (ushort_t)atomicAdd(&hist[qoff + d], 1);  // LDS: replica-local rank
            J.pw[e] = ((uint_t)f2bf(J.w[e]) << 16) | (uint_t)J.src[e];
        }
    }
    __syncthreads();
    // one global atomic per touched bin: reserve [base, base+tot); write back
    // per-replica bases (exclusive prefix over replicas)
    for (int b = tid; b < nb; b += 1024) {
        int c[8];
        int tot = 0;
#pragma unroll
        for (int q = 0; q < 8; ++q) {
            c[q] = (q < rep) ? hist[q * nb + b] : 0;
            tot += c[q];
        }
        if (tot > 0) {
            int run = atomicAdd(&J.deg[b], tot);
#pragma unroll
            for (int q = 0; q < 8; ++q) {
                if (q < rep) {
                    hist[q * nb + b] = run;
                    run += c[q];
                }
            }
        }
    }
    __syncthreads();
#pragma unroll
    for (int u = 0; u < 16; ++u) {
        int e = e0 + u * 1024 + tid;
        if (e < J.E) {
            int d = J.dst[e];  // re-read: L2-hot from pass A
            J.rank[e] = (ushort_t)(hist[qoff + d] + (int)lrk[u]);
        }
    }
}

// ===== merged dispatch: CSR scan (6 blocks) | weight transpose | emb gather =====
// r6: the 6-block scan left 250 CUs idle for its serial latency — backfill with
// the transposes (2040 blocks) + emb gather (35), which are only needed later.
struct ScanPrepArgs {
    const int* deg_base;
    int* offs_base;
    TrBatch tb;
    int bsT;
    const float* emb;
    const int* pidx;
    ushort_t* hp;
    int nEmb;
};
__global__ __launch_bounds__(1024) void sc_scan_prep(ScanPrepArgs sa) {
    __shared__ int wsum[16];
    __shared__ int carry;
    __shared__ ushort_t tt[32 * 33];
    int bx = blockIdx.x;
    const int tid = threadIdx.x;
    if (bx >= 6) {
        bx -= 6;
        if (bx < sa.bsT) {  // 32x32 f32->bf16 transpose, one pass (1024 thr)
            int r = 0;
#pragma unroll
            for (int i = 1; i < 6; ++i) r = (bx >= sa.tb.j[i].bstart) ? i : r;
            const TrJob& J = sa.tb.j[r];
            int local = bx - J.bstart;
            int b = local / J.nxy, rem = local % J.nxy;
            int n0 = (rem % J.nx) * 32, k0 = (rem / J.nx) * 32;
            const float* s = J.src + (size_t)b * J.K * J.N;
            ushort_t* d = J.dst + (size_t)b * J.K * J.N;
            int x = tid & 31, y = tid >> 5;
            {
                int k = k0 + y, n = n0 + x;
                tt[y * 33 + x] =
                    (k < J.K && n < J.N) ? f2bf(s[(size_t)k * J.N + n]) : (ushort_t)0;
            }
            __syncthreads();
            {
                int n = n0 + y, k = k0 + x;
                if (n < J.N && k < J.K) d[(size_t)n * J.K + k] = tt[x * 33 + y];
            }
            return;
        }
        bx -= sa.bsT;
        int i = bx * 1024 + tid;
        if (i < sa.nEmb) {
            int r = i >> 8, c = i & 255;
            int j = sa.pidx[r];
            j = (uint_t)j < (uint_t)NPP ? j : 0;
            sa.hp[i] = f2bf(sa.emb[(size_t)j * 256 + c]);
        }
        return;
    }
    // ---- scan role (shfl-based, 3 barriers per 1024-chunk) ----
    const int ndst[6] = {NCC, NGG, NPP, NGG, NGG, NPP};
    const int dstart[6] = {0, NCC, NCC + NGG, NCC + NGG + NPP, NCC + 2 * NGG + NPP,
                           NCC + 3 * NGG + NPP};
    const int ostart[6] = {0, NCC + 1, NCC + NGG + 2, NCC + NGG + NPP + 3,
                           NCC + 2 * NGG + NPP + 4, NCC + 3 * NGG + NPP + 5};
    int r = bx;
    const int* deg = sa.deg_base + dstart[r];
    int* offs = sa.offs_base + ostart[r];
    int n = ndst[r];
    int wave = tid >> 6, lane = tid & 63;
    if (tid == 0) carry = 0;
    __syncthreads();
    for (int base = 0; base < n; base += 1024) {
        int i = base + tid;
        int v = (i < n) ? deg[i] : 0;
        int x = v;
#pragma unroll
        for (int o = 1; o < 64; o <<= 1) {
            int tv = __shfl_up(x, o, 64);
            if (lane >= o) x += tv;
        }
        if (lane == 63) wsum[wave] = x;
        __syncthreads();
        if (tid == 0) {
            int acc = 0;
#pragma unroll
            for (int k = 0; k < 16; ++k) {
                int tv = wsum[k];
                wsum[k] = acc;
                acc += tv;
            }
        }
        __syncthreads();
        int incl = x + wsum[wave];
        int cr = carry;
        if (i < n) offs[i] = cr + incl - v;
        __syncthreads();
        if (tid == 1023) carry = cr + incl;
        __syncthreads();
    }
    if (tid == 0) offs[n] = carry;
}

// ---------------- merged: CSR fill + emb GEMMs (64x64 tiles, bf16 A) ----------------
// r2: bf16 A (pre-converted), 64x64 tiles -> 768 GEMM blocks, LDS 22.5KB.
// r3: cell job writes C twice — hist (ldc 768, concat layout) AND hc_cmp
// (ldc 256, compact 4MB) for the rev_obs gather.
struct Emb64Job {
    const ushort_t* A;   // bf16 [M][512]
    const ushort_t* Bt;  // bf16 [256][512]
    const float* bias;
    ushort_t* C;
    int ldc;
    ushort_t* C2;  // optional compact copy (ldc 256)
    int mstart;    // prefix of 64-row m-blocks
};
struct FillGemmArgs {
    Emb64Job ej[2];
    int gemmBlocks;  // total mblocks * 4 (mb = bx>>2, ntile = bx&3)
    FillBatch fb;
};
__global__ __launch_bounds__(256) void sc_fill_gemm(FillGemmArgs fg) {
    __shared__ __align__(16) ushort_t As[64 * LDS_STR];
    __shared__ __align__(16) ushort_t Bs[64 * LDS_STR];
    int bx = blockIdx.x;
    if (bx >= fg.gemmBlocks) {
        bx -= fg.gemmBlocks;
        int r = 0;
#pragma unroll
        for (int i = 1; i < 6; ++i) r = (bx >= fg.fb.j[i].bstart) ? i : r;
        const FillJob& J = fg.fb.j[r];
        int e = (bx - J.bstart) * 256 + threadIdx.x;
        if (e < J.E) {
            int d = J.dst[e];
            J.ep[J.offs[d] + (int)J.rank[e]] = J.pw[e];
        }
        return;
    }
    const int mb = bx >> 2, n0 = (bx & 3) * 64;
    const int r = (mb >= fg.ej[1].mstart) ? 1 : 0;
    const Emb64Job& J = fg.ej[r];
    const int m0 = (mb - J.mstart) * 64;  // M is a multiple of 64 for both jobs
    const ushort_t* A = J.A;
    const ushort_t* Bt = J.Bt;
    const int tid = threadIdx.x;
    const int wave = tid >> 6, lane = tid & 63;
    const int lr = lane & 15, lq = lane >> 4;
    f32x4 acc[4] = {};
    for (int k0 = 0; k0 < 512; k0 += 64) {
        __syncthreads();
#pragma unroll
        for (int i = 0; i < 2; ++i) {
            int g = tid + i * 256;
            int rr = g >> 3, c = (g & 7) * 8;
            *(ushortx8*)(&As[rr * LDS_STR + c]) =
                *(const ushortx8*)(A + (size_t)(m0 + rr) * 512 + k0 + c);
            *(ushortx8*)(&Bs[rr * LDS_STR + c]) =
                *(const ushortx8*)(Bt + (size_t)(n0 + rr) * 512 + k0 + c);
        }
        __syncthreads();
#pragma unroll
        for (int kk = 0; kk < 64; kk += 32) {
            bf16x8 a = __builtin_bit_cast(
                bf16x8, *(const ushortx8*)(&As[(wave * 16 + lr) * LDS_STR + kk + lq * 8]));
            bf16x8 b0 =
                __builtin_bit_cast(bf16x8, *(const ushortx8*)(&Bs[(lr)*LDS_STR + kk + lq * 8]));
            bf16x8 b1 = __builtin_bit_cast(
                bf16x8, *(const ushortx8*)(&Bs[(16 + lr) * LDS_STR + kk + lq * 8]));
            bf16x8 b2 = __builtin_bit_cast(
                bf16x8, *(const ushortx8*)(&Bs[(32 + lr) * LDS_STR + kk + lq * 8]));
            bf16x8 b3 = __builtin_bit_cast(
                bf16x8, *(const ushortx8*)(&Bs[(48 + lr) * LDS_STR + kk + lq * 8]));
            acc[0] = __builtin_amdgcn_mfma_f32_16x16x32_bf16(a, b0, acc[0], 0, 0, 0);
            acc[1] = __builtin_amdgcn_mfma_f32_16x16x32_bf16(a, b1, acc[1], 0, 0, 0);
            acc[2] = __builtin_amdgcn_mfma_f32_16x16x32_bf16(a, b2, acc[2], 0, 0, 0);
            acc[3] = __builtin_amdgcn_mfma_f32_16x16x32_bf16(a, b3, acc[3], 0, 0, 0);
        }
    }
#pragma unroll
    for (int nt = 0; nt < 4; ++nt) {
        int col = n0 + nt * 16 + lr;
        float bb = J.bias[col];
#pragma unroll
        for (int v = 0; v < 4; ++v) {
            int row = m0 + wave * 16 + lq * 4 + v;
            ushort_t val = f2bf(scrub(acc[nt][v] + bb));
            J.C[(size_t)row * J.ldc + col] = val;
            if (J.C2) J.C2[(size_t)row * 256 + col] = val;
        }
    }
}

// ---- merged: {mlp + 6 SAGE self-pass} GEMMs + neighbor-mean gather ----
// Gather (r1/r3 form — measured floor ~44us; r2 pipelining and r4 XCD-partition
// regressed, reverted). r5: mlp GEMM merged in (rode along for ~+2us,
// MfmaUtil 0.87%). r7: the SAGE SELF pass (dstf @ W_self + bias, 2.7 GFLOP)
// also depends only on LN outputs — merged here too. Post-gather kernel is
// then neigh-only (half the serial GEMM work). GEMM blocks are PROPORTIONALLY
// INTERLEAVED (floor(bx*G/T) counting) — 1816 GEMM blocks issued first would
// fill the 7-blocks/CU LDS cap and serialize; interleave keeps every CU on a
// gather+GEMM mix (the r5 overlap mechanism).
struct GatherJob {
    const ushort_t* hsrc;
    int src_ld, src_n;
    const int* offs;
    const uint_t* ep;
    ushort_t* out;
    int row_start;
};
struct GMJob {  // 64x64-tile GEMM job: C[M][256] = A[M][*] @ Bt[256][256]^T + bias
    const ushort_t* A;
    int lda;
    const ushort_t* Bt;
    const float* bias;
    ushort_t* C;
    int M;
    int mstart;  // prefix of 64-row m-blocks
};
struct GatherMlpArgs {
    GatherJob j[6];
    GMJob g[7];      // [0]=mlp, [1..6]=self passes
    int gemmBlocks;  // total mblocks*4
    int totalBlocks;
    int total_rows;
};
__global__ __launch_bounds__(256) void sc_gather_mlp(GatherMlpArgs ga) {
    __shared__ __align__(16) ushort_t As[64 * LDS_STR];
    __shared__ __align__(16) ushort_t Bs[64 * LDS_STR];
    const int bx = blockIdx.x;
    const int tid = threadIdx.x;
    const long long G = ga.gemmBlocks, T = ga.totalBlocks;
    const int prev = (int)(((long long)bx * G) / T);  // GEMM blocks before bx
    const int nxt = (int)(((long long)(bx + 1) * G) / T);
    if (nxt > prev) {  // ---- GEMM role (64x64 tile, K=256) ----
        const int gb = prev;
        const int mb = gb >> 2, n0 = (gb & 3) * 64;
        int r = 0;
#pragma unroll
        for (int i = 1; i < 7; ++i) r = (mb >= ga.g[i].mstart) ? i : r;
        const GMJob& J = ga.g[r];
        const int m0 = (mb - J.mstart) * 64;
        const int M = J.M;
        const int wave = tid >> 6, lane = tid & 63;
        const int lr = lane & 15, lq = lane >> 4;
        f32x4 acc[4] = {};
        for (int k0 = 0; k0 < 256; k0 += 64) {
            __syncthreads();
#pragma unroll
            for (int i = 0; i < 2; ++i) {
                int g = tid + i * 256;
                int rr = g >> 3, c = (g & 7) * 8;
                int gm = m0 + rr;
                ushortx8 v = {0, 0, 0, 0, 0, 0, 0, 0};
                if (gm < M) v = *(const ushortx8*)(J.A + (size_t)gm * J.lda + k0 + c);
                *(ushortx8*)(&As[rr * LDS_STR + c]) = v;
                *(ushortx8*)(&Bs[rr * LDS_STR + c]) =
                    *(const ushortx8*)(J.Bt + (size_t)(n0 + rr) * 256 + k0 + c);
            }
            __syncthreads();
#pragma unroll
            for (int kk = 0; kk < 64; kk += 32) {
                bf16x8 a = __builtin_bit_cast(
                    bf16x8, *(const ushortx8*)(&As[(wave * 16 + lr) * LDS_STR + kk + lq * 8]));
                bf16x8 b0 = __builtin_bit_cast(
                    bf16x8, *(const ushortx8*)(&Bs[(lr)*LDS_STR + kk + lq * 8]));
                bf16x8 b1 = __builtin_bit_cast(
                    bf16x8, *(const ushortx8*)(&Bs[(16 + lr) * LDS_STR + kk + lq * 8]));
                bf16x8 b2 = __builtin_bit_cast(
                    bf16x8, *(const ushortx8*)(&Bs[(32 + lr) * LDS_STR + kk + lq * 8]));
                bf16x8 b3 = __builtin_bit_cast(
                    bf16x8, *(const ushortx8*)(&Bs[(48 + lr) * LDS_STR + kk + lq * 8]));
                acc[0] = __builtin_amdgcn_mfma_f32_16x16x32_bf16(a, b0, acc[0], 0, 0, 0);
                acc[1] = __builtin_amdgcn_mfma_f32_16x16x32_bf16(a, b1, acc[1], 0, 0, 0);
                acc[2] = __builtin_amdgcn_mfma_f32_16x16x32_bf16(a, b2, acc[2], 0, 0, 0);
                acc[3] = __builtin_amdgcn_mfma_f32_16x16x32_bf16(a, b3, acc[3], 0, 0, 0);
            }
        }
#pragma unroll
        for (int nt = 0; nt < 4; ++nt) {
            int col = n0 + nt * 16 + lr;
            float bb = J.bias[col];
#pragma unroll
            for (int v = 0; v < 4; ++v) {
                int row = m0 + wave * 16 + lq * 4 + v;
                if (row >= M) continue;
                J.C[(size_t)row * 256 + col] = f2bf(scrub(acc[nt][v] + bb));
            }
        }
        return;
    }
    // ---- gather role ----
    int grow = (bx - prev) * 4 + (tid >> 6);
    if (grow >= ga.total_rows) return;
    int r = 0;
#pragma unroll
    for (int i = 1; i < 6; ++i) r = (grow >= ga.j[i].row_start) ? i : r;
    r = __builtin_amdgcn_readfirstlane(r);  // wave-uniform: scalar descriptor loads
    const char* hsrc = (const char*)ga.j[r].hsrc;
    const uint_t row_bytes = (uint_t)(ga.j[r].src_ld * 2);
    const uint_t src_n = (uint_t)ga.j[r].src_n;
    const int* offs = ga.j[r].offs;
    const uint_t* ep = ga.j[r].ep;
    ushort_t* out = ga.j[r].out;
    int row = grow - ga.j[r].row_start;
    int lane = tid & 63;
    int cb = lane * 8;  // byte offset of this lane's 4 channels (2 dwords)
    int s0 = offs[row], s1 = offs[row + 1];
    float a0 = 0.f, a1 = 0.f, a2 = 0.f, a3 = 0.f;
    for (int base = s0; base < s1; base += 64) {
        int e = base + lane;
        uint_t myp = (e < s1) ? ep[e] : 0u;  // pad lanes: src=0, w=bf16(0)=+0
        int cnt = s1 - base;
        cnt = cnt < 64 ? cnt : 64;
        int cnt16 = (cnt + 15) & ~15;  // padded groups add w=0 terms
        for (int jj = 0; jj < cnt16; jj += 16) {
#pragma unroll
            for (int u = 0; u < 16; ++u) {  // 16 independent saddr gathers in flight
                // readlane -> SGPR: unpack/clamp/addr all run on the scalar pipe
                uint_t pw = (uint_t)__builtin_amdgcn_readlane((int)myp, jj + u);
                uint_t s = pw & 0xFFFFu;
                s = s < src_n ? s : 0u;  // clamp: defects->wrong, not wild
                float w = bf2f((ushort_t)(pw >> 16));  // s_lshl; SGPR operand of v_fma
                const uint2 v = *(const uint2*)(hsrc + (size_t)(s * row_bytes) + cb);
                uint_t x0 = v.x << 16, x1 = v.x & 0xFFFF0000u;
                uint_t x2 = v.y << 16, x3 = v.y & 0xFFFF0000u;
                a0 = fmaf(w, __builtin_bit_cast(float, x0), a0);
                a1 = fmaf(w, __builtin_bit_cast(float, x1), a1);
                a2 = fmaf(w, __builtin_bit_cast(float, x2), a2);
                a3 = fmaf(w, __builtin_bit_cast(float, x3), a3);
            }
        }
    }
    float inv = 1.f / fmaxf((float)(s1 - s0), 1.f);
    ushort_t* o = out + (size_t)row * 256 + lane * 4;
    o[0] = f2bf(scrub(a0 * inv));
    o[1] = f2bf(scrub(a1 * inv));
    o[2] = f2bf(scrub(a2 * inv));
    o[3] = f2bf(scrub(a3 * inv));
}

// ---------------- 6 relation neigh-pass GEMMs (64x64, accumulate onto self) ----------------
// r7: self pass moved into the gather dispatch; this kernel does C += n_* @ W_neigh.
// C holds bf16(self+bias) — read-modify-write epilogue (one extra bf16 rounding
// of the partial sum; LN downstream normalizes).
struct NeighJob {
    const ushort_t* A;   // n_*, lda 256
    const ushort_t* Bt;  // Wt_neigh slice [256][256]
    ushort_t* C;         // s_* (holds self+bias)
    int M;
    int mstart;  // prefix of 64-row m-blocks
};
struct NeighBatch {
    NeighJob j[6];
};
__global__ __launch_bounds__(256) void sc_gemm_neigh(NeighBatch gb) {
    __shared__ __align__(16) ushort_t As[64 * LDS_STR];
    __shared__ __align__(16) ushort_t Bs[64 * LDS_STR];
    const int mbx = blockIdx.x, n0 = blockIdx.y * 64;
    int r = 0;
#pragma unroll
    for (int i = 1; i < 6; ++i) r = (mbx >= gb.j[i].mstart) ? i : r;
    const NeighJob& J = gb.j[r];
    const int m0 = (mbx - J.mstart) * 64;
    const int M = J.M;
    const int tid = threadIdx.x;
    const int wave = tid >> 6, lane = tid & 63;
    const int lr = lane & 15, lq = lane >> 4;
    f32x4 acc[4] = {};
    for (int k0 = 0; k0 < 256; k0 += 64) {
        __syncthreads();
#pragma unroll
        for (int i = 0; i < 2; ++i) {
            int g = tid + i * 256;
            int rr = g >> 3, c = (g & 7) * 8;
            int gm = m0 + rr;
            ushortx8 v = {0, 0, 0, 0, 0, 0, 0, 0};
            if (gm < M) v = *(const ushortx8*)(J.A + (size_t)gm * 256 + k0 + c);
            *(ushortx8*)(&As[rr * LDS_STR + c]) = v;
            *(ushortx8*)(&Bs[rr * LDS_STR + c]) =
                *(const ushortx8*)(J.Bt + (size_t)(n0 + rr) * 256 + k0 + c);
        }
        __syncthreads();
#pragma unroll
        for (int kk = 0; kk < 64; kk += 32) {
            bf16x8 a = __builtin_bit_cast(
                bf16x8, *(const ushortx8*)(&As[(wave * 16 + lr) * LDS_STR + kk + lq * 8]));
            bf16x8 b0 =
                __builtin_bit_cast(bf16x8, *(const ushortx8*)(&Bs[(lr)*LDS_STR + kk + lq * 8]));
            bf16x8 b1 = __builtin_bit_cast(
                bf16x8, *(const ushortx8*)(&Bs[(16 + lr) * LDS_STR + kk + lq * 8]));
            bf16x8 b2 = __builtin_bit_cast(
                bf16x8, *(const ushortx8*)(&Bs[(32 + lr) * LDS_STR + kk + lq * 8]));
            bf16x8 b3 = __builtin_bit_cast(
                bf16x8, *(const ushortx8*)(&Bs[(48 + lr) * LDS_STR + kk + lq * 8]));
            acc[0] = __builtin_amdgcn_mfma_f32_16x16x32_bf16(a, b0, acc[0], 0, 0, 0);
            acc[1] = __builtin_amdgcn_mfma_f32_16x16x32_bf16(a, b1, acc[1], 0, 0, 0);
            acc[2] = __builtin_amdgcn_mfma_f32_16x16x32_bf16(a, b2, acc[2], 0, 0, 0);
            acc[3] = __builtin_amdgcn_mfma_f32_16x16x32_bf16(a, b3, acc[3], 0, 0, 0);
        }
    }
#pragma unroll
    for (int nt = 0; nt < 4; ++nt) {
        int col = n0 + nt * 16 + lr;
#pragma unroll
        for (int v = 0; v < 4; ++v) {
            int row = m0 + wave * 16 + lq * 4 + v;
            if (row >= M) continue;
            size_t idx = (size_t)row * 256 + col;
            J.C[idx] = f2bf(scrub(bf2f(J.C[idx]) + acc[nt][v]));
        }
    }
}

// ---------------- standalone MFMA bf16 GEMM (final proj, f32 out) ----------------
__global__ __launch_bounds__(256) void sc_gemm(const ushort_t* __restrict__ A1, int lda1,
                                               const ushort_t* __restrict__ Bt1, int K1,
                                               const float* __restrict__ bias,
                                               float* __restrict__ Cf, int ldc, int M, int N) {
    __shared__ __align__(16) ushort_t As[128 * LDS_STR];
    __shared__ __align__(16) ushort_t Bs[64 * LDS_STR];
    const int tid = threadIdx.x;
    const int wave = tid >> 6, lane = tid & 63;
    const int lr = lane & 15, lq = lane >> 4;
    const int m0 = blockIdx.x * 128, n0 = blockIdx.y * 64;
    f32x4 acc[2][4] = {};
    for (int k0 = 0; k0 < K1; k0 += 64) {
        __syncthreads();
#pragma unroll
        for (int i = 0; i < 4; ++i) {
            int g = tid + i * 256;
            int r = g >> 3, c = (g & 7) * 8;
            ushortx8 v = {0, 0, 0, 0, 0, 0, 0, 0};
            int gm = m0 + r;
            if (gm < M) v = *(const ushortx8*)(A1 + (size_t)gm * lda1 + k0 + c);
            *(ushortx8*)(&As[r * LDS_STR + c]) = v;
        }
#pragma unroll
        for (int i = 0; i < 2; ++i) {
            int g = tid + i * 256;
            int r = g >> 3, c = (g & 7) * 8;
            ushortx8 v = {0, 0, 0, 0, 0, 0, 0, 0};
            int gn = n0 + r;
            if (gn < N) v = *(const ushortx8*)(Bt1 + (size_t)gn * K1 + k0 + c);
            *(ushortx8*)(&Bs[r * LDS_STR + c]) = v;
        }
        __syncthreads();
#pragma unroll
        for (int kk = 0; kk < 64; kk += 32) {
            bf16x8 a0 = __builtin_bit_cast(
                bf16x8, *(const ushortx8*)(&As[(wave * 32 + lr) * LDS_STR + kk + lq * 8]));
            bf16x8 a1 = __builtin_bit_cast(
                bf16x8, *(const ushortx8*)(&As[(wave * 32 + 16 + lr) * LDS_STR + kk + lq * 8]));
            bf16x8 b0 =
                __builtin_bit_cast(bf16x8, *(const ushortx8*)(&Bs[(lr)*LDS_STR + kk + lq * 8]));
            bf16x8 b1 = __builtin_bit_cast(
                bf16x8, *(const ushortx8*)(&Bs[(16 + lr) * LDS_STR + kk + lq * 8]));
            bf16x8 b2 = __builtin_bit_cast(
                bf16x8, *(const ushortx8*)(&Bs[(32 + lr) * LDS_STR + kk + lq * 8]));
            bf16x8 b3 = __builtin_bit_cast(
                bf16x8, *(const ushortx8*)(&Bs[(48 + lr) * LDS_STR + kk + lq * 8]));
            acc[0][0] = __builtin_amdgcn_mfma_f32_16x16x32_bf16(a0, b0, acc[0][0], 0, 0, 0);
            acc[0][1] = __builtin_amdgcn_mfma_f32_16x16x32_bf16(a0, b1, acc[0][1], 0, 0, 0);
            acc[0][2] = __builtin_amdgcn_mfma_f32_16x16x32_bf16(a0, b2, acc[0][2], 0, 0, 0);
            acc[0][3] = __builtin_amdgcn_mfma_f32_16x16x32_bf16(a0, b3, acc[0][3], 0, 0, 0);
            acc[1][0] = __builtin_amdgcn_mfma_f32_16x16x32_bf16(a1, b0, acc[1][0], 0, 0, 0);
            acc[1][1] = __builtin_amdgcn_mfma_f32_16x16x32_bf16(a1, b1, acc[1][1], 0, 0, 0);
            acc[1][2] = __builtin_amdgcn_mfma_f32_16x16x32_bf16(a1, b2, acc[1][2], 0, 0, 0);
            acc[1][3] = __builtin_amdgcn_mfma_f32_16x16x32_bf16(a1, b3, acc[1][3], 0, 0, 0);
        }
    }
#pragma unroll
    for (int mt = 0; mt < 2; ++mt)
#pragma unroll
        for (int nt = 0; nt < 4; ++nt) {
            int col = n0 + nt * 16 + lr;
            if (col >= N) continue;
            float bb = bias ? bias[col] : 0.f;
#pragma unroll
            for (int v = 0; v < 4; ++v) {
                int row = m0 + wave * 32 + mt * 16 + lq * 4 + v;
                if (row >= M) continue;
                Cf[(size_t)row * ldc + col] = scrub(acc[mt][nt][v] + bb);
            }
        }
}

// ---------------- fused selu+LN chains, 3 node types in one dispatch ----------------
struct LnJob {
    const ushort_t *sA, *sB, *sC;
    const float *g1, *b1, *g2, *b2;
    ushort_t* out;
    int out_ld;
    ushort_t* out2;  // optional compact copy (ld 256)
    int row_start;
};
struct LnBatch {
    LnJob j[3];
};
__global__ __launch_bounds__(256) void sc_fuse_ln_all(LnBatch lb, int total_rows) {
    int grow = blockIdx.x * 4 + (threadIdx.x >> 6);
    if (grow >= total_rows) return;
    int r = 0;
#pragma unroll
    for (int i = 1; i < 3; ++i) r = (grow >= lb.j[i].row_start) ? i : r;
    r = __builtin_amdgcn_readfirstlane(r);
    const ushort_t* srcs[3] = {lb.j[r].sA, lb.j[r].sB, lb.j[r].sC};
    const float* g1 = lb.j[r].g1;
    const float* b1 = lb.j[r].b1;
    const float* g2 = lb.j[r].g2;
    const float* b2 = lb.j[r].b2;
    ushort_t* out = lb.j[r].out;
    int out_ld = lb.j[r].out_ld;
    ushort_t* out2 = lb.j[r].out2;
    int row = grow - lb.j[r].row_start;
    int lane = threadIdx.x & 63, c = lane * 4;
    float t[4] = {0.f, 0.f, 0.f, 0.f};
#pragma unroll
    for (int si = 0; si < 3; ++si) {
        const ushort_t* s = srcs[si];
        if (!s) continue;
        ushortx4 v = *(const ushortx4*)(s + (size_t)row * 256 + c);
        float x0 = selu_f(scrub(bf2f(v[0]))), x1 = selu_f(scrub(bf2f(v[1])));
        float x2 = selu_f(scrub(bf2f(v[2]))), x3 = selu_f(scrub(bf2f(v[3])));
        float mu = wsum64(x0 + x1 + x2 + x3) * (1.f / 256.f);
        float d0 = x0 - mu, d1 = x1 - mu, d2 = x2 - mu, d3 = x3 - mu;
        float var = wsum64(d0 * d0 + d1 * d1 + d2 * d2 + d3 * d3) * (1.f / 256.f);
        float rr = rsqrtf(var + 1e-5f);
        t[0] += d0 * rr * g1[c + 0] + b1[c + 0];
        t[1] += d1 * rr * g1[c + 1] + b1[c + 1];
        t[2] += d2 * rr * g1[c + 2] + b1[c + 2];
        t[3] += d3 * rr * g1[c + 3] + b1[c + 3];
    }
    float x0 = selu_f(scrub(t[0])), x1 = selu_f(scrub(t[1]));
    float x2 = selu_f(scrub(t[2])), x3 = selu_f(scrub(t[3]));
    float mu = wsum64(x0 + x1 + x2 + x3) * (1.f / 256.f);
    float d0 = x0 - mu, d1 = x1 - mu, d2 = x2 - mu, d3 = x3 - mu;
    float var = wsum64(d0 * d0 + d1 * d1 + d2 * d2 + d3 * d3) * (1.f / 256.f);
    float rr = rsqrtf(var + 1e-5f);
    ushort_t o0 = f2bf(scrub(d0 * rr * g2[c + 0] + b2[c + 0]));
    ushort_t o1 = f2bf(scrub(d1 * rr * g2[c + 1] + b2[c + 1]));
    ushort_t o2v = f2bf(scrub(d2 * rr * g2[c + 2] + b2[c + 2]));
    ushort_t o3 = f2bf(scrub(d3 * rr * g2[c + 3] + b2[c + 3]));
    ushort_t* o = out + (size_t)row * out_ld + c;
    o[0] = o0;
    o[1] = o1;
    o[2] = o2v;
    o[3] = o3;
    if (out2) {
        ushort_t* q = out2 + (size_t)row * 256 + c;
        q[0] = o0;
        q[1] = o1;
        q[2] = o2v;
        q[3] = o3;
    }
}

static inline int cdivi(int a, int b) { return (a + b - 1) / b; }

extern "C" void kernel_launch(void* const* d_in, const int* in_sizes, int n_in, void* d_out,
                              int out_size, void* d_ws, size_t ws_size, hipStream_t stream) {
    const float* cell_feat = (const float*)d_in[0];
    const float* gene_feat = (const float*)d_in[1];
    const int* pro_idx = (const int*)d_in[2];
    const int* edge_src[6] = {(const int*)d_in[3],  (const int*)d_in[6],  (const int*)d_in[9],
                              (const int*)d_in[12], (const int*)d_in[15], (const int*)d_in[18]};
    const int* edge_dst[6] = {(const int*)d_in[4],  (const int*)d_in[7],  (const int*)d_in[10],
                              (const int*)d_in[13], (const int*)d_in[16], (const int*)d_in[19]};
    const float* edge_w[6] = {(const float*)d_in[5],  (const float*)d_in[8],
                              (const float*)d_in[11], (const float*)d_in[14],
                              (const float*)d_in[17], (const float*)d_in[20]};
    const float* W_emb_cell = (const float*)d_in[21];
    const float* b_emb_cell = (const float*)d_in[22];
    const float* W_emb_gene = (const float*)d_in[23];
    const float* b_emb_gene = (const float*)d_in[24];
    const float* emb_pro = (const float*)d_in[25];
    const float* W_mlpcell = (const float*)d_in[26];
    const float* b_mlpcell = (const float*)d_in[27];
    const float* W_sage_self = (const float*)d_in[28];
    const float* W_sage_neigh = (const float*)d_in[29];
    const float* b_sage = (const float*)d_in[30];
    const float* ln1_g = (const float*)d_in[31];
    const float* ln1_b = (const float*)d_in[32];
    const float* ln2_g = (const float*)d_in[33];
    const float* ln2_b = (const float*)d_in[34];
    const float* W_last = (const float*)d_in[35];
    const float* b_last = (const float*)d_in[36];

    const int E_obs = in_sizes[3], E_sym = in_sizes[9], E_coexp = in_sizes[15],
              E_ppi = in_sizes[18];
    const int Er[6] = {E_obs, E_obs, E_sym, E_sym, E_coexp, E_ppi};
    const int Nd[6] = {NCC, NGG, NPP, NGG, NGG, NPP};

    // ---- workspace carve ----
    char* p = (char*)d_ws;
    auto carve = [&](size_t bytes) -> char* {
        char* r = p;
        p += ((bytes + 255) & ~(size_t)255);
        return r;
    };
    ushort_t* hist = (ushort_t*)carve((size_t)NCC * 768 * 2);
    ushort_t* hg = (ushort_t*)carve((size_t)NGG * 256 * 2);
    ushort_t* hp = (ushort_t*)carve((size_t)NPP * 256 * 2);
    ushort_t* n_obs = (ushort_t*)carve((size_t)NCC * 256 * 2);
    ushort_t* n_robs = (ushort_t*)carve((size_t)NGG * 256 * 2);
    ushort_t* n_sym = (ushort_t*)carve((size_t)NPP * 256 * 2);
    ushort_t* n_rsym = (ushort_t*)carve((size_t)NGG * 256 * 2);
    ushort_t* n_coexp = (ushort_t*)carve((size_t)NGG * 256 * 2);
    ushort_t* n_ppi = (ushort_t*)carve((size_t)NPP * 256 * 2);
    ushort_t* s_obs = (ushort_t*)carve((size_t)NCC * 256 * 2);
    ushort_t* s_robs = (ushort_t*)carve((size_t)NGG * 256 * 2);
    ushort_t* s_sym = (ushort_t*)carve((size_t)NPP * 256 * 2);
    ushort_t* s_rsym = (ushort_t*)carve((size_t)NGG * 256 * 2);
    ushort_t* s_coexp = (ushort_t*)carve((size_t)NGG * 256 * 2);
    ushort_t* s_ppi = (ushort_t*)carve((size_t)NPP * 256 * 2);
    ushort_t* s_mlp = (ushort_t*)carve((size_t)NCC * 256 * 2);
    ushort_t* Wt_emb_cell = (ushort_t*)carve((size_t)512 * 256 * 2);
    ushort_t* Wt_emb_gene = (ushort_t*)carve((size_t)512 * 256 * 2);
    ushort_t* Wt_mlp = (ushort_t*)carve((size_t)2 * 256 * 256 * 2);
    ushort_t* Wt_self = (ushort_t*)carve((size_t)12 * 256 * 256 * 2);
    ushort_t* Wt_neigh = (ushort_t*)carve((size_t)12 * 256 * 256 * 2);
    ushort_t* Wt_last = (ushort_t*)carve((size_t)140 * 768 * 2);
    const int NDTOT = NCC + 3 * NGG + 2 * NPP;  // 20760
    int* deg_all = (int*)carve((size_t)NDTOT * 4);
    int* offs_all = (int*)carve((size_t)(NDTOT + 6) * 4);
    const int ETOT = 2 * E_obs + 2 * E_sym + E_coexp + E_ppi;
    uint_t* pw_all = (uint_t*)carve((size_t)ETOT * 4);        // packed, edge order
    ushort_t* rank_all = (ushort_t*)carve((size_t)ETOT * 2);  // rank within dst group
    uint_t* ep_all = (uint_t*)carve((size_t)ETOT * 4);        // packed, CSR order
    ushort_t* hc_cmp = (ushort_t*)carve((size_t)NCC * 256 * 2);  // compact cell reps (4MB)
    // bf16 feats ALIAS the s_* region (dead until the layer-0 gather dispatch
    // writes the self-pass outputs; cf16/gf16 are fully consumed by
    // sc_fill_gemm which runs before that).
    ushort_t* cf16 = s_obs;    // [NCC][512] bf16
    ushort_t* gf16 = s_coexp;  // [NGG][512] bf16
    (void)ws_size;
    (void)n_in;
    (void)out_size;

    const int dS[6] = {0, NCC, NCC + NGG, NCC + NGG + NPP, NCC + 2 * NGG + NPP,
                       NCC + 3 * NGG + NPP};
    const int oS[6] = {0, NCC + 1, NCC + NGG + 2, NCC + NGG + NPP + 3, NCC + 2 * NGG + NPP + 4,
                       NCC + 3 * NGG + NPP + 5};
    int eS[6];
    eS[0] = 0;
    eS[1] = eS[0] + E_obs;
    eS[2] = eS[1] + E_obs;
    eS[3] = eS[2] + E_sym;
    eS[4] = eS[3] + E_sym;
    eS[5] = eS[4] + E_coexp;

    // ---- zero deg, then merged: count (REP hist) | cvt ----
    sc_zero1<<<cdivi(NDTOT, 256), 256, 0, stream>>>(deg_all, NDTOT);
    {
        CountArgs ca;
        int bs = 0;
        for (int r = 0; r < 6; ++r) {
            ca.cb.j[r] = {edge_dst[r], edge_src[r], edge_w[r], pw_all + eS[r], rank_all + eS[r],
                          Er[r],       Nd[r],       deg_all + dS[r], bs};
            bs += cdivi(Er[r], CEPB);
        }
        ca.bsC = bs;
        ca.cf = cell_feat;
        ca.cf16 = cf16;
        ca.nbC = (NCC * 512) / 8192;  // 512 blocks, exact
        ca.gf = gene_feat;
        ca.gf16 = gf16;
        int nbG = (NGG * 512) / 8192;  // 256 blocks, exact
        sc_count<<<bs + ca.nbC + nbG, 1024, 0, stream>>>(ca);
    }
    // ---- merged: CSR scan (6 blocks) | weight transposes | emb gather ----
    {
        ScanPrepArgs sa;
        sa.deg_base = deg_all;
        sa.offs_base = offs_all;
        int bt = 0;
        auto add = [&](int idx, const float* s, ushort_t* d, int B, int K, int N) {
            int nx = cdivi(N, 32), ny = cdivi(K, 32);
            sa.tb.j[idx] = {s, d, K, N, nx, nx * ny, bt};
            bt += B * nx * ny;
        };
        add(0, W_emb_cell, Wt_emb_cell, 1, 512, 256);
        add(1, W_emb_gene, Wt_emb_gene, 1, 512, 256);
        add(2, W_mlpcell, Wt_mlp, 2, 256, 256);
        add(3, W_sage_self, Wt_self, 12, 256, 256);
        add(4, W_sage_neigh, Wt_neigh, 12, 256, 256);
        add(5, W_last, Wt_last, 1, 768, 140);
        sa.bsT = bt;
        sa.emb = emb_pro;
        sa.pidx = pro_idx;
        sa.hp = hp;
        sa.nEmb = NPP * 256;
        int bsE = cdivi(NPP * 256, 1024);  // 35 blocks, exact
        sc_scan_prep<<<6 + bt + bsE, 1024, 0, stream>>>(sa);
    }
    // ---- merged: CSR fill + both emb GEMMs (64x64 tiles, bf16 A) ----
    {
        FillGemmArgs fg;
        fg.ej[0] = {cf16, Wt_emb_cell, b_emb_cell, hist, 768, hc_cmp, 0};
        fg.ej[1] = {gf16, Wt_emb_gene, b_emb_gene, hg, 256, nullptr, NCC / 64};
        fg.gemmBlocks = (NCC / 64 + NGG / 64) * 4;  // 192 mblocks * 4 ntiles = 768
        int bs = 0;
        for (int r = 0; r < 6; ++r) {
            fg.fb.j[r] = {edge_dst[r], pw_all + eS[r], rank_all + eS[r], Er[r], offs_all + oS[r],
                          ep_all + eS[r], bs};
            bs += cdivi(Er[r], 256);
        }
        sc_fill_gemm<<<fg.gemmBlocks + bs, 256, 0, stream>>>(fg);
    }

    // ---- layers ----
    const size_t WSZ = 65536;
    for (int l = 0; l < 2; ++l) {
        const ushort_t* hc_l = hist + l * 256;  // row stride 768
        const ushort_t* dstf[6] = {hc_l, hg, hp, hg, hg, hp};
        const int dld[6] = {768, 256, 256, 256, 256, 256};
        const ushort_t* nbuf[6] = {n_obs, n_robs, n_sym, n_rsym, n_coexp, n_ppi};
        ushort_t* so[6] = {s_obs, s_robs, s_sym, s_rsym, s_coexp, s_ppi};
        // merged: {mlp + 6 self-pass} GEMMs (depend only on LN outputs) + all
        // 6 neighbor-mean gathers, proportionally interleaved
        {
            GatherMlpArgs ga;
            const ushort_t* hs[6] = {hg, hc_cmp, hg, hp, hg, hp};
            const int sn[6] = {NGG, NCC, NGG, NPP, NGG, NPP};
            int rs = 0;
            for (int r = 0; r < 6; ++r) {
                ga.j[r] = {hs[r], 256, sn[r], offs_all + oS[r], ep_all + eS[r],
                           (ushort_t*)nbuf[r], rs};
                rs += Nd[r];
            }
            ga.g[0] = {hc_l, 768, Wt_mlp + (size_t)l * WSZ, b_mlpcell + l * 256, s_mlp, NCC, 0};
            int msg = NCC / 64;
            for (int r = 0; r < 6; ++r) {
                ga.g[r + 1] = {dstf[r],
                               dld[r],
                               Wt_self + (size_t)(l * 6 + r) * WSZ,
                               b_sage + (l * 6 + r) * 256,
                               so[r],
                               Nd[r],
                               msg};
                msg += cdivi(Nd[r], 64);
            }
            ga.gemmBlocks = msg * 4;
            int gBlocks = cdivi(rs, 4);
            ga.totalBlocks = ga.gemmBlocks + gBlocks;
            ga.total_rows = rs;
            sc_gather_mlp<<<ga.totalBlocks, 256, 0, stream>>>(ga);
        }
        // neigh-pass GEMMs: s_* += n_* @ W_neigh
        {
            NeighBatch nb;
            int ms = 0;
            for (int r = 0; r < 6; ++r) {
                nb.j[r] = {nbuf[r], Wt_neigh + (size_t)(l * 6 + r) * WSZ, so[r], Nd[r], ms};
                ms += cdivi(Nd[r], 64);
            }
            sc_gemm_neigh<<<dim3(ms, 4), 256, 0, stream>>>(nb);
        }
        // 3 fused selu+LN chains in one dispatch; cell job also writes compact
        // hc_cmp for the next layer's rev_obs gather (only needed for l==0)
        {
            LnBatch lb;
            lb.j[0] = {s_robs, s_rsym, s_coexp, ln1_g + (l * 3 + 0) * 256,
                       ln1_b + (l * 3 + 0) * 256, ln2_g + (l * 3 + 0) * 256,
                       ln2_b + (l * 3 + 0) * 256, hg, 256, nullptr, 0};
            lb.j[1] = {s_sym, s_ppi, nullptr, ln1_g + (l * 3 + 1) * 256,
                       ln1_b + (l * 3 + 1) * 256, ln2_g + (l * 3 + 1) * 256,
                       ln2_b + (l * 3 + 1) * 256, hp, 256, nullptr, NGG};
            lb.j[2] = {s_obs, s_mlp, nullptr, ln1_g + (l * 3 + 2) * 256,
                       ln1_b + (l * 3 + 2) * 256, ln2_g + (l * 3 + 2) * 256,
                       ln2_b + (l * 3 + 2) * 256, hist + (l + 1) * 256, 768,
                       (l == 0) ? hc_cmp : nullptr, NGG + NPP};
            int rs = NGG + NPP + NCC;
            sc_fuse_ln_all<<<cdivi(rs, 4), 256, 0, stream>>>(lb, rs);
        }
    }

    // ---- final projection: out(f32) = hist[8192,768] @ W_last + b_last ----
    sc_gemm<<<dim3(64, 3), 256, 0, stream>>>(hist, 768, Wt_last, 768, b_last, (float*)d_out, 140,
                                             NCC, 140);
}

// Round 9
// 362.245 us; speedup vs baseline: 1.0416x; 1.0416x over previous
//
#include <hip/hip_runtime.h>

typedef unsigned short ushort_t;
typedef unsigned int uint_t;

typedef ushort_t ushortx8 __attribute__((ext_vector_type(8)));
typedef ushort_t ushortx4 __attribute__((ext_vector_type(4)));
typedef __bf16 bf16x8 __attribute__((ext_vector_type(8)));
typedef float f32x4 __attribute__((ext_vector_type(4)));

#define NCC 8192
#define NGG 4096
#define NPP 140
// LDS tile row stride (elements): multiple of 8 so ushortx8 (align 16) LDS ops
// are 16B-aligned; bank step 44 dwords == 12 mod 32 => 2-way aliasing (free).
#define LDS_STR 88
// Count kernel: edges per block (1024 thr x 16). Bigger => better atomic dedup,
// fewer blocks => less CU parallelism. 16K: ~270K global atomics vs 850K flat.
#define CEPB 16384

__device__ __forceinline__ float bf2f(ushort_t u) {
    uint_t i = ((uint_t)u) << 16;
    float f;
    __builtin_memcpy(&f, &i, 4);
    return f;
}
__device__ __forceinline__ ushort_t f2bf(float f) {
    uint_t i;
    __builtin_memcpy(&i, &f, 4);
    uint_t r = (i + 0x7FFFu + ((i >> 16) & 1u)) >> 16;
    return (ushort_t)r;
}
__device__ __forceinline__ float scrub(float x) {  // insurance: non-finite -> 0
    return __builtin_isfinite(x) ? x : 0.f;
}
__device__ __forceinline__ float selu_f(float x) {
    return x > 0.f ? 1.0507009873554805f * x : 1.7580993408473766f * expm1f(x);
}
__device__ __forceinline__ float wsum64(float x) {
    for (int o = 32; o; o >>= 1) x += __shfl_xor(x, o, 64);
    return x;
}

// ---------------- zero fill ----------------
__global__ __launch_bounds__(256) void sc_zero1(int* __restrict__ a, int na) {
    int i = blockIdx.x * 256 + threadIdx.x;
    if (i < na) a[i] = 0;
}

// ================= job structs =================
struct CountJob {
    const int* dst;
    const int* src;
    const float* w;
    uint_t* pw;      // packed (bf16(w)<<16)|src, edge order
    ushort_t* rank;  // rank within dst group
    int E;
    int nbins;
    int* deg;
    int bstart;
};
struct CountBatch {
    CountJob j[6];
};
struct TrJob {
    const float* src;
    ushort_t* dst;
    int K, N, nx, nxy;
    int bstart;
};
struct TrBatch {
    TrJob j[6];
};
struct FillJob {
    const int* dst;
    const uint_t* pw;
    const ushort_t* rank;
    int E;
    const int* offs;
    uint_t* ep;
    int bstart;
};
struct FillBatch {
    FillJob j[6];
};

// ===== merged dispatch: degree count (replicated LDS hist) | feat bf16 cvt =====
// r0: LDS-hist dedup cut 850K global atomics to ~270K (53us -> off top-5).
// r2: backfilled with the f32->bf16 feature cvt (768 BW-bound blocks).
// r6: REPLICATED histogram — sym/ppi push 16K edges into 140 bins (~117
// same-address LDS-atomic RMWs per bin per block, serialized). REP=8 replicas
// for nb<=1024 (REP=2 for 4096, 1 for 8192) cut same-address contention 8x.
// Pass B prefix-sums replicas into one global range reservation; ranks unique.
struct CountArgs {
    CountBatch cb;
    int bsC;
    const float* cf;
    ushort_t* cf16;
    int nbC;  // cell cvt blocks (8192 elems each)
    const float* gf;
    ushort_t* gf16;
};
__global__ __launch_bounds__(1024) void sc_count(CountArgs ca) {
    __shared__ int hist[NCC];  // 32KB; [0, nb*rep) used
    int bx = blockIdx.x;
    const int tid = threadIdx.x;
    if (bx >= ca.bsC) {  // ---- cvt role ----
        bx -= ca.bsC;
        const float* src;
        ushort_t* dst;
        if (bx < ca.nbC) {
            src = ca.cf;
            dst = ca.cf16;
        } else {
            bx -= ca.nbC;
            src = ca.gf;
            dst = ca.gf16;
        }
        size_t i = ((size_t)bx * 1024 + tid) * 8;  // spans exact multiples of 8192
        float4 f0 = *(const float4*)(src + i);
        float4 f1 = *(const float4*)(src + i + 4);
        ushortx8 v;
        v[0] = f2bf(f0.x);
        v[1] = f2bf(f0.y);
        v[2] = f2bf(f0.z);
        v[3] = f2bf(f0.w);
        v[4] = f2bf(f1.x);
        v[5] = f2bf(f1.y);
        v[6] = f2bf(f1.z);
        v[7] = f2bf(f1.w);
        *(ushortx8*)(dst + i) = v;
        return;
    }
    int r = 0;
#pragma unroll
    for (int i = 1; i < 6; ++i) r = (bx >= ca.cb.j[i].bstart) ? i : r;
    const CountJob& J = ca.cb.j[r];
    const int nb = J.nbins;
    const int rep = nb <= 1024 ? 8 : (nb <= 4096 ? 2 : 1);
    const int qoff = (tid & (rep - 1)) * nb;
    const int tot_bins = nb * rep;  // <= NCC by construction
    for (int b = tid; b < tot_bins; b += 1024) hist[b] = 0;
    __syncthreads();
    const int e0 = (bx - J.bstart) * CEPB;
    ushort_t lrk[16];
#pragma unroll
    for (int u = 0; u < 16; ++u) {
        int e = e0 + u * 1024 + tid;
        if (e < J.E) {
            int d = J.dst[e];
            lrk[u] = (ushort_t)atomicAdd(&hist[qoff + d], 1);  // LDS: replica-local rank
            J.pw[e] = ((uint_t)f2bf(J.w[e]) << 16) | (uint_t)J.src[e];
        }
    }
    __syncthreads();
    // one global atomic per touched bin: reserve [base, base+tot); write back
    // per-replica bases (exclusive prefix over replicas)
    for (int b = tid; b < nb; b += 1024) {
        int c[8];
        int tot = 0;
#pragma unroll
        for (int q = 0; q < 8; ++q) {
            c[q] = (q < rep) ? hist[q * nb + b] : 0;
            tot += c[q];
        }
        if (tot > 0) {
            int run = atomicAdd(&J.deg[b], tot);
#pragma unroll
            for (int q = 0; q < 8; ++q) {
                if (q < rep) {
                    hist[q * nb + b] = run;
                    run += c[q];
                }
            }
        }
    }
    __syncthreads();
#pragma unroll
    for (int u = 0; u < 16; ++u) {
        int e = e0 + u * 1024 + tid;
        if (e < J.E) {
            int d = J.dst[e];  // re-read: L2-hot from pass A
            J.rank[e] = (ushort_t)(hist[qoff + d] + (int)lrk[u]);
        }
    }
}

// ===== merged dispatch: CSR scan (6 blocks) | weight transpose | emb gather =====
// r6: the 6-block scan left 250 CUs idle for its serial latency — backfill with
// the transposes (2040 blocks) + emb gather (35), which are only needed later.
struct ScanPrepArgs {
    const int* deg_base;
    int* offs_base;
    TrBatch tb;
    int bsT;
    const float* emb;
    const int* pidx;
    ushort_t* hp;
    int nEmb;
};
__global__ __launch_bounds__(1024) void sc_scan_prep(ScanPrepArgs sa) {
    __shared__ int wsum[16];
    __shared__ int carry;
    __shared__ ushort_t tt[32 * 33];
    int bx = blockIdx.x;
    const int tid = threadIdx.x;
    if (bx >= 6) {
        bx -= 6;
        if (bx < sa.bsT) {  // 32x32 f32->bf16 transpose, one pass (1024 thr)
            int r = 0;
#pragma unroll
            for (int i = 1; i < 6; ++i) r = (bx >= sa.tb.j[i].bstart) ? i : r;
            const TrJob& J = sa.tb.j[r];
            int local = bx - J.bstart;
            int b = local / J.nxy, rem = local % J.nxy;
            int n0 = (rem % J.nx) * 32, k0 = (rem / J.nx) * 32;
            const float* s = J.src + (size_t)b * J.K * J.N;
            ushort_t* d = J.dst + (size_t)b * J.K * J.N;
            int x = tid & 31, y = tid >> 5;
            {
                int k = k0 + y, n = n0 + x;
                tt[y * 33 + x] =
                    (k < J.K && n < J.N) ? f2bf(s[(size_t)k * J.N + n]) : (ushort_t)0;
            }
            __syncthreads();
            {
                int n = n0 + y, k = k0 + x;
                if (n < J.N && k < J.K) d[(size_t)n * J.K + k] = tt[x * 33 + y];
            }
            return;
        }
        bx -= sa.bsT;
        int i = bx * 1024 + tid;
        if (i < sa.nEmb) {
            int r = i >> 8, c = i & 255;
            int j = sa.pidx[r];
            j = (uint_t)j < (uint_t)NPP ? j : 0;
            sa.hp[i] = f2bf(sa.emb[(size_t)j * 256 + c]);
        }
        return;
    }
    // ---- scan role (shfl-based, 3 barriers per 1024-chunk) ----
    const int ndst[6] = {NCC, NGG, NPP, NGG, NGG, NPP};
    const int dstart[6] = {0, NCC, NCC + NGG, NCC + NGG + NPP, NCC + 2 * NGG + NPP,
                           NCC + 3 * NGG + NPP};
    const int ostart[6] = {0, NCC + 1, NCC + NGG + 2, NCC + NGG + NPP + 3,
                           NCC + 2 * NGG + NPP + 4, NCC + 3 * NGG + NPP + 5};
    int r = bx;
    const int* deg = sa.deg_base + dstart[r];
    int* offs = sa.offs_base + ostart[r];
    int n = ndst[r];
    int wave = tid >> 6, lane = tid & 63;
    if (tid == 0) carry = 0;
    __syncthreads();
    for (int base = 0; base < n; base += 1024) {
        int i = base + tid;
        int v = (i < n) ? deg[i] : 0;
        int x = v;
#pragma unroll
        for (int o = 1; o < 64; o <<= 1) {
            int tv = __shfl_up(x, o, 64);
            if (lane >= o) x += tv;
        }
        if (lane == 63) wsum[wave] = x;
        __syncthreads();
        if (tid == 0) {
            int acc = 0;
#pragma unroll
            for (int k = 0; k < 16; ++k) {
                int tv = wsum[k];
                wsum[k] = acc;
                acc += tv;
            }
        }
        __syncthreads();
        int incl = x + wsum[wave];
        int cr = carry;
        if (i < n) offs[i] = cr + incl - v;
        __syncthreads();
        if (tid == 1023) carry = cr + incl;
        __syncthreads();
    }
    if (tid == 0) offs[n] = carry;
}

// ---------------- merged: CSR fill + emb GEMMs (64x64 tiles, bf16 A) ----------------
// r2: bf16 A (pre-converted), 64x64 tiles -> 768 GEMM blocks, LDS 22.5KB.
// r3: cell job writes C twice — hist (ldc 768, concat layout) AND hc_cmp
// (ldc 256, compact 4MB) for the rev_obs gather.
struct Emb64Job {
    const ushort_t* A;   // bf16 [M][512]
    const ushort_t* Bt;  // bf16 [256][512]
    const float* bias;
    ushort_t* C;
    int ldc;
    ushort_t* C2;  // optional compact copy (ldc 256)
    int mstart;    // prefix of 64-row m-blocks
};
struct FillGemmArgs {
    Emb64Job ej[2];
    int gemmBlocks;  // total mblocks * 4 (mb = bx>>2, ntile = bx&3)
    FillBatch fb;
};
__global__ __launch_bounds__(256) void sc_fill_gemm(FillGemmArgs fg) {
    __shared__ __align__(16) ushort_t As[64 * LDS_STR];
    __shared__ __align__(16) ushort_t Bs[64 * LDS_STR];
    int bx = blockIdx.x;
    if (bx >= fg.gemmBlocks) {
        bx -= fg.gemmBlocks;
        int r = 0;
#pragma unroll
        for (int i = 1; i < 6; ++i) r = (bx >= fg.fb.j[i].bstart) ? i : r;
        const FillJob& J = fg.fb.j[r];
        int e = (bx - J.bstart) * 256 + threadIdx.x;
        if (e < J.E) {
            int d = J.dst[e];
            J.ep[J.offs[d] + (int)J.rank[e]] = J.pw[e];
        }
        return;
    }
    const int mb = bx >> 2, n0 = (bx & 3) * 64;
    const int r = (mb >= fg.ej[1].mstart) ? 1 : 0;
    const Emb64Job& J = fg.ej[r];
    const int m0 = (mb - J.mstart) * 64;  // M is a multiple of 64 for both jobs
    const ushort_t* A = J.A;
    const ushort_t* Bt = J.Bt;
    const int tid = threadIdx.x;
    const int wave = tid >> 6, lane = tid & 63;
    const int lr = lane & 15, lq = lane >> 4;
    f32x4 acc[4] = {};
    for (int k0 = 0; k0 < 512; k0 += 64) {
        __syncthreads();
#pragma unroll
        for (int i = 0; i < 2; ++i) {
            int g = tid + i * 256;
            int rr = g >> 3, c = (g & 7) * 8;
            *(ushortx8*)(&As[rr * LDS_STR + c]) =
                *(const ushortx8*)(A + (size_t)(m0 + rr) * 512 + k0 + c);
            *(ushortx8*)(&Bs[rr * LDS_STR + c]) =
                *(const ushortx8*)(Bt + (size_t)(n0 + rr) * 512 + k0 + c);
        }
        __syncthreads();
#pragma unroll
        for (int kk = 0; kk < 64; kk += 32) {
            bf16x8 a = __builtin_bit_cast(
                bf16x8, *(const ushortx8*)(&As[(wave * 16 + lr) * LDS_STR + kk + lq * 8]));
            bf16x8 b0 =
                __builtin_bit_cast(bf16x8, *(const ushortx8*)(&Bs[(lr)*LDS_STR + kk + lq * 8]));
            bf16x8 b1 = __builtin_bit_cast(
                bf16x8, *(const ushortx8*)(&Bs[(16 + lr) * LDS_STR + kk + lq * 8]));
            bf16x8 b2 = __builtin_bit_cast(
                bf16x8, *(const ushortx8*)(&Bs[(32 + lr) * LDS_STR + kk + lq * 8]));
            bf16x8 b3 = __builtin_bit_cast(
                bf16x8, *(const ushortx8*)(&Bs[(48 + lr) * LDS_STR + kk + lq * 8]));
            acc[0] = __builtin_amdgcn_mfma_f32_16x16x32_bf16(a, b0, acc[0], 0, 0, 0);
            acc[1] = __builtin_amdgcn_mfma_f32_16x16x32_bf16(a, b1, acc[1], 0, 0, 0);
            acc[2] = __builtin_amdgcn_mfma_f32_16x16x32_bf16(a, b2, acc[2], 0, 0, 0);
            acc[3] = __builtin_amdgcn_mfma_f32_16x16x32_bf16(a, b3, acc[3], 0, 0, 0);
        }
    }
#pragma unroll
    for (int nt = 0; nt < 4; ++nt) {
        int col = n0 + nt * 16 + lr;
        float bb = J.bias[col];
#pragma unroll
        for (int v = 0; v < 4; ++v) {
            int row = m0 + wave * 16 + lq * 4 + v;
            ushort_t val = f2bf(scrub(acc[nt][v] + bb));
            J.C[(size_t)row * J.ldc + col] = val;
            if (J.C2) J.C2[(size_t)row * 256 + col] = val;
        }
    }
}

// ---------------- merged: mlp GEMM + SAGE neighbor-mean gather ----------------
// Gather (r1/r3 form — measured floor ~44us; r2 pipelining and r4 XCD-partition
// both regressed, reverted): scalar-pipe edge descriptors, unroll-16 ILP,
// compact hc_cmp source for rev_obs. r5: mlp GEMM merged in to backfill idle
// issue slots — measured: rides along for ~+2us (MfmaUtil 0.87%).
// r7 LESSON (reverted): adding the 6 self-pass GEMMs too (1816 rider blocks)
// exceeded the idle-slot bubble — marginal cost jumped to ~100% (44->55us,
// bank conflicts 327K->1.16M). 512 rider blocks is the working operating point.
struct GatherJob {
    const ushort_t* hsrc;
    int src_ld, src_n;
    const int* offs;
    const uint_t* ep;
    ushort_t* out;
    int row_start;
};
struct GatherMlpArgs {
    GatherJob j[6];
    int gemmBlocks;      // 128 mblocks * 4 ntiles = 512
    const ushort_t* mA;  // hc_l, lda 768
    const ushort_t* mBt; // Wt_mlp layer slice, [256][256]
    const float* mbias;
    ushort_t* mC;        // s_mlp [8192][256]
    int total_rows;
};
__global__ __launch_bounds__(256) void sc_gather_mlp(GatherMlpArgs ga) {
    __shared__ __align__(16) ushort_t As[64 * LDS_STR];
    __shared__ __align__(16) ushort_t Bs[64 * LDS_STR];
    int bx = blockIdx.x;
    const int tid = threadIdx.x;
    if (bx < ga.gemmBlocks) {  // ---- mlp GEMM role (64x64 tile, K=256) ----
        const int mb = bx >> 2, n0 = (bx & 3) * 64;
        const int m0 = mb * 64;
        const int wave = tid >> 6, lane = tid & 63;
        const int lr = lane & 15, lq = lane >> 4;
        f32x4 acc[4] = {};
        for (int k0 = 0; k0 < 256; k0 += 64) {
            __syncthreads();
#pragma unroll
            for (int i = 0; i < 2; ++i) {
                int g = tid + i * 256;
                int rr = g >> 3, c = (g & 7) * 8;
                *(ushortx8*)(&As[rr * LDS_STR + c]) =
                    *(const ushortx8*)(ga.mA + (size_t)(m0 + rr) * 768 + k0 + c);
                *(ushortx8*)(&Bs[rr * LDS_STR + c]) =
                    *(const ushortx8*)(ga.mBt + (size_t)(n0 + rr) * 256 + k0 + c);
            }
            __syncthreads();
#pragma unroll
            for (int kk = 0; kk < 64; kk += 32) {
                bf16x8 a = __builtin_bit_cast(
                    bf16x8, *(const ushortx8*)(&As[(wave * 16 + lr) * LDS_STR + kk + lq * 8]));
                bf16x8 b0 = __builtin_bit_cast(
                    bf16x8, *(const ushortx8*)(&Bs[(lr)*LDS_STR + kk + lq * 8]));
                bf16x8 b1 = __builtin_bit_cast(
                    bf16x8, *(const ushortx8*)(&Bs[(16 + lr) * LDS_STR + kk + lq * 8]));
                bf16x8 b2 = __builtin_bit_cast(
                    bf16x8, *(const ushortx8*)(&Bs[(32 + lr) * LDS_STR + kk + lq * 8]));
                bf16x8 b3 = __builtin_bit_cast(
                    bf16x8, *(const ushortx8*)(&Bs[(48 + lr) * LDS_STR + kk + lq * 8]));
                acc[0] = __builtin_amdgcn_mfma_f32_16x16x32_bf16(a, b0, acc[0], 0, 0, 0);
                acc[1] = __builtin_amdgcn_mfma_f32_16x16x32_bf16(a, b1, acc[1], 0, 0, 0);
                acc[2] = __builtin_amdgcn_mfma_f32_16x16x32_bf16(a, b2, acc[2], 0, 0, 0);
                acc[3] = __builtin_amdgcn_mfma_f32_16x16x32_bf16(a, b3, acc[3], 0, 0, 0);
            }
        }
#pragma unroll
        for (int nt = 0; nt < 4; ++nt) {
            int col = n0 + nt * 16 + lr;
            float bb = ga.mbias[col];
#pragma unroll
            for (int v = 0; v < 4; ++v) {
                int row = m0 + wave * 16 + lq * 4 + v;
                ga.mC[(size_t)row * 256 + col] = f2bf(scrub(acc[nt][v] + bb));
            }
        }
        return;
    }
    // ---- gather role ----
    bx -= ga.gemmBlocks;
    int grow = bx * 4 + (tid >> 6);
    if (grow >= ga.total_rows) return;
    int r = 0;
#pragma unroll
    for (int i = 1; i < 6; ++i) r = (grow >= ga.j[i].row_start) ? i : r;
    r = __builtin_amdgcn_readfirstlane(r);  // wave-uniform: scalar descriptor loads
    const char* hsrc = (const char*)ga.j[r].hsrc;
    const uint_t row_bytes = (uint_t)(ga.j[r].src_ld * 2);
    const uint_t src_n = (uint_t)ga.j[r].src_n;
    const int* offs = ga.j[r].offs;
    const uint_t* ep = ga.j[r].ep;
    ushort_t* out = ga.j[r].out;
    int row = grow - ga.j[r].row_start;
    int lane = tid & 63;
    int cb = lane * 8;  // byte offset of this lane's 4 channels (2 dwords)
    int s0 = offs[row], s1 = offs[row + 1];
    float a0 = 0.f, a1 = 0.f, a2 = 0.f, a3 = 0.f;
    for (int base = s0; base < s1; base += 64) {
        int e = base + lane;
        uint_t myp = (e < s1) ? ep[e] : 0u;  // pad lanes: src=0, w=bf16(0)=+0
        int cnt = s1 - base;
        cnt = cnt < 64 ? cnt : 64;
        int cnt16 = (cnt + 15) & ~15;  // padded groups add w=0 terms
        for (int jj = 0; jj < cnt16; jj += 16) {
#pragma unroll
            for (int u = 0; u < 16; ++u) {  // 16 independent saddr gathers in flight
                // readlane -> SGPR: unpack/clamp/addr all run on the scalar pipe
                uint_t pw = (uint_t)__builtin_amdgcn_readlane((int)myp, jj + u);
                uint_t s = pw & 0xFFFFu;
                s = s < src_n ? s : 0u;  // clamp: defects->wrong, not wild
                float w = bf2f((ushort_t)(pw >> 16));  // s_lshl; SGPR operand of v_fma
                const uint2 v = *(const uint2*)(hsrc + (size_t)(s * row_bytes) + cb);
                uint_t x0 = v.x << 16, x1 = v.x & 0xFFFF0000u;
                uint_t x2 = v.y << 16, x3 = v.y & 0xFFFF0000u;
                a0 = fmaf(w, __builtin_bit_cast(float, x0), a0);
                a1 = fmaf(w, __builtin_bit_cast(float, x1), a1);
                a2 = fmaf(w, __builtin_bit_cast(float, x2), a2);
                a3 = fmaf(w, __builtin_bit_cast(float, x3), a3);
            }
        }
    }
    float inv = 1.f / fmaxf((float)(s1 - s0), 1.f);
    ushort_t* o = out + (size_t)row * 256 + lane * 4;
    o[0] = f2bf(scrub(a0 * inv));
    o[1] = f2bf(scrub(a1 * inv));
    o[2] = f2bf(scrub(a2 * inv));
    o[3] = f2bf(scrub(a3 * inv));
}

// ---------------- 6 relation SAGE GEMMs, 64x64 tiles ----------------
// r6: was 128x64 tile + 33.8KB LDS -> 656 blocks = 2.6/CU against a 4/CU cap:
// ~1-2 resident blocks/CU, so stage->barrier->MFMA ran un-overlapped. 64x64 +
// 22.5KB LDS -> 1304 blocks = 5.1/CU under a 7/CU cap (same fix as r2's emb
// GEMM). r7's attempt to move the self pass into the gather dispatch regressed
// (rider-block bubble exceeded) — self+neigh both stay here.
struct Sage64Job {
    const ushort_t* A1;  // dst feats
    int lda1;
    const ushort_t* Bt1;  // self weights [256][256]
    const ushort_t* A2;   // neighbor means, lda 256
    const ushort_t* Bt2;  // neigh weights
    const float* bias;
    ushort_t* C;  // ldc 256
    int M;
    int mstart;  // prefix of 64-row m-blocks
};
struct Sage64Batch {
    Sage64Job j[6];
};
__global__ __launch_bounds__(256) void sc_gemm_batch64(Sage64Batch gb) {
    __shared__ __align__(16) ushort_t As[64 * LDS_STR];
    __shared__ __align__(16) ushort_t Bs[64 * LDS_STR];
    const int mbx = blockIdx.x, n0 = blockIdx.y * 64;
    int r = 0;
#pragma unroll
    for (int i = 1; i < 6; ++i) r = (mbx >= gb.j[i].mstart) ? i : r;
    const Sage64Job& J = gb.j[r];
    const int m0 = (mbx - J.mstart) * 64;
    const int M = J.M;
    const int tid = threadIdx.x;
    const int wave = tid >> 6, lane = tid & 63;
    const int lr = lane & 15, lq = lane >> 4;
    f32x4 acc[4] = {};
    for (int pass = 0; pass < 2; ++pass) {
        const ushort_t* A = pass ? J.A2 : J.A1;
        const int lda = pass ? 256 : J.lda1;
        const ushort_t* Bt = pass ? J.Bt2 : J.Bt1;
        for (int k0 = 0; k0 < 256; k0 += 64) {
            __syncthreads();
#pragma unroll
            for (int i = 0; i < 2; ++i) {
                int g = tid + i * 256;
                int rr = g >> 3, c = (g & 7) * 8;
                int gm = m0 + rr;
                ushortx8 v = {0, 0, 0, 0, 0, 0, 0, 0};
                if (gm < M) v = *(const ushortx8*)(A + (size_t)gm * lda + k0 + c);
                *(ushortx8*)(&As[rr * LDS_STR + c]) = v;
                *(ushortx8*)(&Bs[rr * LDS_STR + c]) =
                    *(const ushortx8*)(Bt + (size_t)(n0 + rr) * 256 + k0 + c);
            }
            __syncthreads();
#pragma unroll
            for (int kk = 0; kk < 64; kk += 32) {
                bf16x8 a = __builtin_bit_cast(
                    bf16x8, *(const ushortx8*)(&As[(wave * 16 + lr) * LDS_STR + kk + lq * 8]));
                bf16x8 b0 = __builtin_bit_cast(
                    bf16x8, *(const ushortx8*)(&Bs[(lr)*LDS_STR + kk + lq * 8]));
                bf16x8 b1 = __builtin_bit_cast(
                    bf16x8, *(const ushortx8*)(&Bs[(16 + lr) * LDS_STR + kk + lq * 8]));
                bf16x8 b2 = __builtin_bit_cast(
                    bf16x8, *(const ushortx8*)(&Bs[(32 + lr) * LDS_STR + kk + lq * 8]));
                bf16x8 b3 = __builtin_bit_cast(
                    bf16x8, *(const ushortx8*)(&Bs[(48 + lr) * LDS_STR + kk + lq * 8]));
                acc[0] = __builtin_amdgcn_mfma_f32_16x16x32_bf16(a, b0, acc[0], 0, 0, 0);
                acc[1] = __builtin_amdgcn_mfma_f32_16x16x32_bf16(a, b1, acc[1], 0, 0, 0);
                acc[2] = __builtin_amdgcn_mfma_f32_16x16x32_bf16(a, b2, acc[2], 0, 0, 0);
                acc[3] = __builtin_amdgcn_mfma_f32_16x16x32_bf16(a, b3, acc[3], 0, 0, 0);
            }
        }
    }
#pragma unroll
    for (int nt = 0; nt < 4; ++nt) {
        int col = n0 + nt * 16 + lr;
        float bb = J.bias[col];
#pragma unroll
        for (int v = 0; v < 4; ++v) {
            int row = m0 + wave * 16 + lq * 4 + v;
            if (row >= M) continue;
            J.C[(size_t)row * 256 + col] = f2bf(scrub(acc[nt][v] + bb));
        }
    }
}

// ---------------- final projection (64x64 tiles, f32 out) ----------------
// r8: was 128x64 tile @33.8KB LDS -> 192 blocks < 256 CUs (under ONE block/CU,
// zero cross-block overlap). 64x64 @22.5KB -> 384 blocks (same occupancy
// mechanism as r2/r6). N-guards for N=140.
__global__ __launch_bounds__(256) void sc_gemm64f(const ushort_t* __restrict__ A1, int lda1,
                                                  const ushort_t* __restrict__ Bt1, int K1,
                                                  const float* __restrict__ bias,
                                                  float* __restrict__ Cf, int ldc, int M,
                                                  int N) {
    __shared__ __align__(16) ushort_t As[64 * LDS_STR];
    __shared__ __align__(16) ushort_t Bs[64 * LDS_STR];
    const int tid = threadIdx.x;
    const int wave = tid >> 6, lane = tid & 63;
    const int lr = lane & 15, lq = lane >> 4;
    const int m0 = blockIdx.x * 64, n0 = blockIdx.y * 64;
    f32x4 acc[4] = {};
    for (int k0 = 0; k0 < K1; k0 += 64) {
        __syncthreads();
#pragma unroll
        for (int i = 0; i < 2; ++i) {
            int g = tid + i * 256;
            int rr = g >> 3, c = (g & 7) * 8;
            int gm = m0 + rr;
            ushortx8 v = {0, 0, 0, 0, 0, 0, 0, 0};
            if (gm < M) v = *(const ushortx8*)(A1 + (size_t)gm * lda1 + k0 + c);
            *(ushortx8*)(&As[rr * LDS_STR + c]) = v;
            int gn = n0 + rr;
            ushortx8 w = {0, 0, 0, 0, 0, 0, 0, 0};
            if (gn < N) w = *(const ushortx8*)(Bt1 + (size_t)gn * K1 + k0 + c);
            *(ushortx8*)(&Bs[rr * LDS_STR + c]) = w;
        }
        __syncthreads();
#pragma unroll
        for (int kk = 0; kk < 64; kk += 32) {
            bf16x8 a = __builtin_bit_cast(
                bf16x8, *(const ushortx8*)(&As[(wave * 16 + lr) * LDS_STR + kk + lq * 8]));
            bf16x8 b0 =
                __builtin_bit_cast(bf16x8, *(const ushortx8*)(&Bs[(lr)*LDS_STR + kk + lq * 8]));
            bf16x8 b1 = __builtin_bit_cast(
                bf16x8, *(const ushortx8*)(&Bs[(16 + lr) * LDS_STR + kk + lq * 8]));
            bf16x8 b2 = __builtin_bit_cast(
                bf16x8, *(const ushortx8*)(&Bs[(32 + lr) * LDS_STR + kk + lq * 8]));
            bf16x8 b3 = __builtin_bit_cast(
                bf16x8, *(const ushortx8*)(&Bs[(48 + lr) * LDS_STR + kk + lq * 8]));
            acc[0] = __builtin_amdgcn_mfma_f32_16x16x32_bf16(a, b0, acc[0], 0, 0, 0);
            acc[1] = __builtin_amdgcn_mfma_f32_16x16x32_bf16(a, b1, acc[1], 0, 0, 0);
            acc[2] = __builtin_amdgcn_mfma_f32_16x16x32_bf16(a, b2, acc[2], 0, 0, 0);
            acc[3] = __builtin_amdgcn_mfma_f32_16x16x32_bf16(a, b3, acc[3], 0, 0, 0);
        }
    }
#pragma unroll
    for (int nt = 0; nt < 4; ++nt) {
        int col = n0 + nt * 16 + lr;
        if (col >= N) continue;
        float bb = bias ? bias[col] : 0.f;
#pragma unroll
        for (int v = 0; v < 4; ++v) {
            int row = m0 + wave * 16 + lq * 4 + v;
            if (row >= M) continue;
            Cf[(size_t)row * ldc + col] = scrub(acc[nt][v] + bb);
        }
    }
}

// ---------------- fused selu+LN chains, 3 node types in one dispatch ----------------
struct LnJob {
    const ushort_t *sA, *sB, *sC;
    const float *g1, *b1, *g2, *b2;
    ushort_t* out;
    int out_ld;
    ushort_t* out2;  // optional compact copy (ld 256)
    int row_start;
};
struct LnBatch {
    LnJob j[3];
};
__global__ __launch_bounds__(256) void sc_fuse_ln_all(LnBatch lb, int total_rows) {
    int grow = blockIdx.x * 4 + (threadIdx.x >> 6);
    if (grow >= total_rows) return;
    int r = 0;
#pragma unroll
    for (int i = 1; i < 3; ++i) r = (grow >= lb.j[i].row_start) ? i : r;
    r = __builtin_amdgcn_readfirstlane(r);
    const ushort_t* srcs[3] = {lb.j[r].sA, lb.j[r].sB, lb.j[r].sC};
    const float* g1 = lb.j[r].g1;
    const float* b1 = lb.j[r].b1;
    const float* g2 = lb.j[r].g2;
    const float* b2 = lb.j[r].b2;
    ushort_t* out = lb.j[r].out;
    int out_ld = lb.j[r].out_ld;
    ushort_t* out2 = lb.j[r].out2;
    int row = grow - lb.j[r].row_start;
    int lane = threadIdx.x & 63, c = lane * 4;
    float t[4] = {0.f, 0.f, 0.f, 0.f};
#pragma unroll
    for (int si = 0; si < 3; ++si) {
        const ushort_t* s = srcs[si];
        if (!s) continue;
        ushortx4 v = *(const ushortx4*)(s + (size_t)row * 256 + c);
        float x0 = selu_f(scrub(bf2f(v[0]))), x1 = selu_f(scrub(bf2f(v[1])));
        float x2 = selu_f(scrub(bf2f(v[2]))), x3 = selu_f(scrub(bf2f(v[3])));
        float mu = wsum64(x0 + x1 + x2 + x3) * (1.f / 256.f);
        float d0 = x0 - mu, d1 = x1 - mu, d2 = x2 - mu, d3 = x3 - mu;
        float var = wsum64(d0 * d0 + d1 * d1 + d2 * d2 + d3 * d3) * (1.f / 256.f);
        float rr = rsqrtf(var + 1e-5f);
        t[0] += d0 * rr * g1[c + 0] + b1[c + 0];
        t[1] += d1 * rr * g1[c + 1] + b1[c + 1];
        t[2] += d2 * rr * g1[c + 2] + b1[c + 2];
        t[3] += d3 * rr * g1[c + 3] + b1[c + 3];
    }
    float x0 = selu_f(scrub(t[0])), x1 = selu_f(scrub(t[1]));
    float x2 = selu_f(scrub(t[2])), x3 = selu_f(scrub(t[3]));
    float mu = wsum64(x0 + x1 + x2 + x3) * (1.f / 256.f);
    float d0 = x0 - mu, d1 = x1 - mu, d2 = x2 - mu, d3 = x3 - mu;
    float var = wsum64(d0 * d0 + d1 * d1 + d2 * d2 + d3 * d3) * (1.f / 256.f);
    float rr = rsqrtf(var + 1e-5f);
    ushort_t o0 = f2bf(scrub(d0 * rr * g2[c + 0] + b2[c + 0]));
    ushort_t o1 = f2bf(scrub(d1 * rr * g2[c + 1] + b2[c + 1]));
    ushort_t o2v = f2bf(scrub(d2 * rr * g2[c + 2] + b2[c + 2]));
    ushort_t o3 = f2bf(scrub(d3 * rr * g2[c + 3] + b2[c + 3]));
    ushort_t* o = out + (size_t)row * out_ld + c;
    o[0] = o0;
    o[1] = o1;
    o[2] = o2v;
    o[3] = o3;
    if (out2) {
        ushort_t* q = out2 + (size_t)row * 256 + c;
        q[0] = o0;
        q[1] = o1;
        q[2] = o2v;
        q[3] = o3;
    }
}

static inline int cdivi(int a, int b) { return (a + b - 1) / b; }

extern "C" void kernel_launch(void* const* d_in, const int* in_sizes, int n_in, void* d_out,
                              int out_size, void* d_ws, size_t ws_size, hipStream_t stream) {
    const float* cell_feat = (const float*)d_in[0];
    const float* gene_feat = (const float*)d_in[1];
    const int* pro_idx = (const int*)d_in[2];
    const int* edge_src[6] = {(const int*)d_in[3],  (const int*)d_in[6],  (const int*)d_in[9],
                              (const int*)d_in[12], (const int*)d_in[15], (const int*)d_in[18]};
    const int* edge_dst[6] = {(const int*)d_in[4],  (const int*)d_in[7],  (const int*)d_in[10],
                              (const int*)d_in[13], (const int*)d_in[16], (const int*)d_in[19]};
    const float* edge_w[6] = {(const float*)d_in[5],  (const float*)d_in[8],
                              (const float*)d_in[11], (const float*)d_in[14],
                              (const float*)d_in[17], (const float*)d_in[20]};
    const float* W_emb_cell = (const float*)d_in[21];
    const float* b_emb_cell = (const float*)d_in[22];
    const float* W_emb_gene = (const float*)d_in[23];
    const float* b_emb_gene = (const float*)d_in[24];
    const float* emb_pro = (const float*)d_in[25];
    const float* W_mlpcell = (const float*)d_in[26];
    const float* b_mlpcell = (const float*)d_in[27];
    const float* W_sage_self = (const float*)d_in[28];
    const float* W_sage_neigh = (const float*)d_in[29];
    const float* b_sage = (const float*)d_in[30];
    const float* ln1_g = (const float*)d_in[31];
    const float* ln1_b = (const float*)d_in[32];
    const float* ln2_g = (const float*)d_in[33];
    const float* ln2_b = (const float*)d_in[34];
    const float* W_last = (const float*)d_in[35];
    const float* b_last = (const float*)d_in[36];

    const int E_obs = in_sizes[3], E_sym = in_sizes[9], E_coexp = in_sizes[15],
              E_ppi = in_sizes[18];
    const int Er[6] = {E_obs, E_obs, E_sym, E_sym, E_coexp, E_ppi};
    const int Nd[6] = {NCC, NGG, NPP, NGG, NGG, NPP};

    // ---- workspace carve ----
    char* p = (char*)d_ws;
    auto carve = [&](size_t bytes) -> char* {
        char* r = p;
        p += ((bytes + 255) & ~(size_t)255);
        return r;
    };
    ushort_t* hist = (ushort_t*)carve((size_t)NCC * 768 * 2);
    ushort_t* hg = (ushort_t*)carve((size_t)NGG * 256 * 2);
    ushort_t* hp = (ushort_t*)carve((size_t)NPP * 256 * 2);
    ushort_t* n_obs = (ushort_t*)carve((size_t)NCC * 256 * 2);
    ushort_t* n_robs = (ushort_t*)carve((size_t)NGG * 256 * 2);
    ushort_t* n_sym = (ushort_t*)carve((size_t)NPP * 256 * 2);
    ushort_t* n_rsym = (ushort_t*)carve((size_t)NGG * 256 * 2);
    ushort_t* n_coexp = (ushort_t*)carve((size_t)NGG * 256 * 2);
    ushort_t* n_ppi = (ushort_t*)carve((size_t)NPP * 256 * 2);
    ushort_t* s_obs = (ushort_t*)carve((size_t)NCC * 256 * 2);
    ushort_t* s_robs = (ushort_t*)carve((size_t)NGG * 256 * 2);
    ushort_t* s_sym = (ushort_t*)carve((size_t)NPP * 256 * 2);
    ushort_t* s_rsym = (ushort_t*)carve((size_t)NGG * 256 * 2);
    ushort_t* s_coexp = (ushort_t*)carve((size_t)NGG * 256 * 2);
    ushort_t* s_ppi = (ushort_t*)carve((size_t)NPP * 256 * 2);
    ushort_t* s_mlp = (ushort_t*)carve((size_t)NCC * 256 * 2);
    ushort_t* Wt_emb_cell = (ushort_t*)carve((size_t)512 * 256 * 2);
    ushort_t* Wt_emb_gene = (ushort_t*)carve((size_t)512 * 256 * 2);
    ushort_t* Wt_mlp = (ushort_t*)carve((size_t)2 * 256 * 256 * 2);
    ushort_t* Wt_self = (ushort_t*)carve((size_t)12 * 256 * 256 * 2);
    ushort_t* Wt_neigh = (ushort_t*)carve((size_t)12 * 256 * 256 * 2);
    ushort_t* Wt_last = (ushort_t*)carve((size_t)140 * 768 * 2);
    const int NDTOT = NCC + 3 * NGG + 2 * NPP;  // 20760
    int* deg_all = (int*)carve((size_t)NDTOT * 4);
    int* offs_all = (int*)carve((size_t)(NDTOT + 6) * 4);
    const int ETOT = 2 * E_obs + 2 * E_sym + E_coexp + E_ppi;
    uint_t* pw_all = (uint_t*)carve((size_t)ETOT * 4);        // packed, edge order
    ushort_t* rank_all = (ushort_t*)carve((size_t)ETOT * 2);  // rank within dst group
    uint_t* ep_all = (uint_t*)carve((size_t)ETOT * 4);        // packed, CSR order
    ushort_t* hc_cmp = (ushort_t*)carve((size_t)NCC * 256 * 2);  // compact cell reps (4MB)
    // bf16 feats ALIAS the s_* region (dead until sc_gemm_batch64 writes them;
    // cf16/gf16 are fully consumed by sc_fill_gemm which runs before that).
    ushort_t* cf16 = s_obs;    // [NCC][512] bf16
    ushort_t* gf16 = s_coexp;  // [NGG][512] bf16
    (void)ws_size;
    (void)n_in;
    (void)out_size;

    const int dS[6] = {0, NCC, NCC + NGG, NCC + NGG + NPP, NCC + 2 * NGG + NPP,
                       NCC + 3 * NGG + NPP};
    const int oS[6] = {0, NCC + 1, NCC + NGG + 2, NCC + NGG + NPP + 3, NCC + 2 * NGG + NPP + 4,
                       NCC + 3 * NGG + NPP + 5};
    int eS[6];
    eS[0] = 0;
    eS[1] = eS[0] + E_obs;
    eS[2] = eS[1] + E_obs;
    eS[3] = eS[2] + E_sym;
    eS[4] = eS[3] + E_sym;
    eS[5] = eS[4] + E_coexp;

    // ---- zero deg, then merged: count (REP hist) | cvt ----
    sc_zero1<<<cdivi(NDTOT, 256), 256, 0, stream>>>(deg_all, NDTOT);
    {
        CountArgs ca;
        int bs = 0;
        for (int r = 0; r < 6; ++r) {
            ca.cb.j[r] = {edge_dst[r], edge_src[r], edge_w[r], pw_all + eS[r], rank_all + eS[r],
                          Er[r],       Nd[r],       deg_all + dS[r], bs};
            bs += cdivi(Er[r], CEPB);
        }
        ca.bsC = bs;
        ca.cf = cell_feat;
        ca.cf16 = cf16;
        ca.nbC = (NCC * 512) / 8192;  // 512 blocks, exact
        ca.gf = gene_feat;
        ca.gf16 = gf16;
        int nbG = (NGG * 512) / 8192;  // 256 blocks, exact
        sc_count<<<bs + ca.nbC + nbG, 1024, 0, stream>>>(ca);
    }
    // ---- merged: CSR scan (6 blocks) | weight transposes | emb gather ----
    {
        ScanPrepArgs sa;
        sa.deg_base = deg_all;
        sa.offs_base = offs_all;
        int bt = 0;
        auto add = [&](int idx, const float* s, ushort_t* d, int B, int K, int N) {
            int nx = cdivi(N, 32), ny = cdivi(K, 32);
            sa.tb.j[idx] = {s, d, K, N, nx, nx * ny, bt};
            bt += B * nx * ny;
        };
        add(0, W_emb_cell, Wt_emb_cell, 1, 512, 256);
        add(1, W_emb_gene, Wt_emb_gene, 1, 512, 256);
        add(2, W_mlpcell, Wt_mlp, 2, 256, 256);
        add(3, W_sage_self, Wt_self, 12, 256, 256);
        add(4, W_sage_neigh, Wt_neigh, 12, 256, 256);
        add(5, W_last, Wt_last, 1, 768, 140);
        sa.bsT = bt;
        sa.emb = emb_pro;
        sa.pidx = pro_idx;
        sa.hp = hp;
        sa.nEmb = NPP * 256;
        int bsE = cdivi(NPP * 256, 1024);  // 35 blocks, exact
        sc_scan_prep<<<6 + bt + bsE, 1024, 0, stream>>>(sa);
    }
    // ---- merged: CSR fill + both emb GEMMs (64x64 tiles, bf16 A) ----
    {
        FillGemmArgs fg;
        fg.ej[0] = {cf16, Wt_emb_cell, b_emb_cell, hist, 768, hc_cmp, 0};
        fg.ej[1] = {gf16, Wt_emb_gene, b_emb_gene, hg, 256, nullptr, NCC / 64};
        fg.gemmBlocks = (NCC / 64 + NGG / 64) * 4;  // 192 mblocks * 4 ntiles = 768
        int bs = 0;
        for (int r = 0; r < 6; ++r) {
            fg.fb.j[r] = {edge_dst[r], pw_all + eS[r], rank_all + eS[r], Er[r], offs_all + oS[r],
                          ep_all + eS[r], bs};
            bs += cdivi(Er[r], 256);
        }
        sc_fill_gemm<<<fg.gemmBlocks + bs, 256, 0, stream>>>(fg);
    }

    // ---- layers ----
    for (int l = 0; l < 2; ++l) {
        const ushort_t* hc_l = hist + l * 256;  // row stride 768
        // merged: mlp GEMM (independent of gathers) + all 6 neighbor-mean gathers
        {
            GatherMlpArgs ga;
            const ushort_t* hs[6] = {hg, hc_cmp, hg, hp, hg, hp};
            const int sn[6] = {NGG, NCC, NGG, NPP, NGG, NPP};
            ushort_t* outs[6] = {n_obs, n_robs, n_sym, n_rsym, n_coexp, n_ppi};
            int rs = 0;
            for (int r = 0; r < 6; ++r) {
                ga.j[r] = {hs[r], 256, sn[r], offs_all + oS[r], ep_all + eS[r], outs[r], rs};
                rs += Nd[r];
            }
            ga.gemmBlocks = (NCC / 64) * 4;  // 512 blocks, issued first
            ga.mA = hc_l;
            ga.mBt = Wt_mlp + (size_t)l * 65536;
            ga.mbias = b_mlpcell + l * 256;
            ga.mC = s_mlp;
            ga.total_rows = rs;
            sc_gather_mlp<<<ga.gemmBlocks + cdivi(rs, 4), 256, 0, stream>>>(ga);
        }
        // 6 relation GEMMs, 64x64 tiles (r6: occupancy fix)
        {
            const size_t WSZ = 65536;
            Sage64Batch gb;
            const ushort_t* dstf[6] = {hc_l, hg, hp, hg, hg, hp};
            const int dld[6] = {768, 256, 256, 256, 256, 256};
            const ushort_t* nb[6] = {n_obs, n_robs, n_sym, n_rsym, n_coexp, n_ppi};
            ushort_t* so[6] = {s_obs, s_robs, s_sym, s_rsym, s_coexp, s_ppi};
            int ms = 0;
            for (int r = 0; r < 6; ++r) {
                gb.j[r] = {dstf[r],
                           dld[r],
                           Wt_self + (size_t)(l * 6 + r) * WSZ,
                           nb[r],
                           Wt_neigh + (size_t)(l * 6 + r) * WSZ,
                           b_sage + (l * 6 + r) * 256,
                           so[r],
                           Nd[r],
                           ms};
                ms += cdivi(Nd[r], 64);
            }
            sc_gemm_batch64<<<dim3(ms, 4), 256, 0, stream>>>(gb);
        }
        // 3 fused selu+LN chains in one dispatch; cell job also writes compact
        // hc_cmp for the next layer's rev_obs gather (only needed for l==0)
        {
            LnBatch lb;
            lb.j[0] = {s_robs, s_rsym, s_coexp, ln1_g + (l * 3 + 0) * 256,
                       ln1_b + (l * 3 + 0) * 256, ln2_g + (l * 3 + 0) * 256,
                       ln2_b + (l * 3 + 0) * 256, hg, 256, nullptr, 0};
            lb.j[1] = {s_sym, s_ppi, nullptr, ln1_g + (l * 3 + 1) * 256,
                       ln1_b + (l * 3 + 1) * 256, ln2_g + (l * 3 + 1) * 256,
                       ln2_b + (l * 3 + 1) * 256, hp, 256, nullptr, NGG};
            lb.j[2] = {s_obs, s_mlp, nullptr, ln1_g + (l * 3 + 2) * 256,
                       ln1_b + (l * 3 + 2) * 256, ln2_g + (l * 3 + 2) * 256,
                       ln2_b + (l * 3 + 2) * 256, hist + (l + 1) * 256, 768,
                       (l == 0) ? hc_cmp : nullptr, NGG + NPP};
            int rs = NGG + NPP + NCC;
            sc_fuse_ln_all<<<cdivi(rs, 4), 256, 0, stream>>>(lb, rs);
        }
    }

    // ---- final projection: out(f32) = hist[8192,768] @ W_last + b_last ----
    sc_gemm64f<<<dim3(NCC / 64, 3), 256, 0, stream>>>(hist, 768, Wt_last, 768, b_last,
                                                      (float*)d_out, 140, NCC, 140);
}